// Round 6
// baseline (887.441 us; speedup 1.0000x reference)
//
#include <hip/hip_runtime.h>
#include <math.h>

#define B_GRAPHS 8192
#define OUT_DIM 1024
#define NU 128
#define NS 8
#define IN_DIM 1160          // OUT_DIM + NU + NS
#define KPAD1 1216           // IN_DIM padded to multiple of 64
#define HID 256
#define NSEG (B_GRAPHS * NU)        // 1048576 = 2^20
#define EDGES (B_GRAPHS * OUT_DIM)  // 8388608 = 2^23

// ---- binning parameters ----
#define BINS 2048
#define SEGS_PER_BIN 512
#define QUARTER (EDGES / 4)         // 2097152 (idx0 passes, u64 records)
#define HALF (EDGES / 2)            // 4194304 (idx1 passes, u32 records)
#define BIN_CAP01 1536              // mean 1024 + 16 sigma; 2048*1536*8B = 24 MiB
#define BIN_CAP2 2880               // mean 2048 + 18 sigma; *4B = 23.6 MB
#define SCHUNK 16384                // edges per scatter block

typedef __attribute__((ext_vector_type(8))) short short8;
typedef __attribute__((ext_vector_type(4))) float f32x4;

__device__ __forceinline__ unsigned short f2bf(float f) {
    unsigned u = __float_as_uint(f);
    const unsigned r = (u >> 16) & 1u;
    return (unsigned short)((u + 0x7fffu + r) >> 16);   // RNE
}

// ================= prep: fp32 -> bf16 conversions ==========================
__global__ __launch_bounds__(256) void convert_feats_kernel(
    const float* __restrict__ u2s, const float* __restrict__ usr,
    const float* __restrict__ srv, unsigned short* __restrict__ F)
{
    const int t = blockIdx.x * 256 + threadIdx.x;   // 8192*152 threads
    const int row = t / 152;
    const int g = t - row * 152;
    const int col = g * 8;
    float v[8];
    if (g < 128) {
        const float4 a = *(const float4*)&u2s[(size_t)row * OUT_DIM + col];
        const float4 b = *(const float4*)&u2s[(size_t)row * OUT_DIM + col + 4];
        v[0]=a.x; v[1]=a.y; v[2]=a.z; v[3]=a.w; v[4]=b.x; v[5]=b.y; v[6]=b.z; v[7]=b.w;
    } else if (g < 144) {
        const int c = col - OUT_DIM;
        const float4 a = *(const float4*)&usr[(size_t)row * NU + c];
        const float4 b = *(const float4*)&usr[(size_t)row * NU + c + 4];
        v[0]=a.x; v[1]=a.y; v[2]=a.z; v[3]=a.w; v[4]=b.x; v[5]=b.y; v[6]=b.z; v[7]=b.w;
    } else if (g == 144) {
        const float4 a = *(const float4*)&srv[(size_t)row * NS];
        const float4 b = *(const float4*)&srv[(size_t)row * NS + 4];
        v[0]=a.x; v[1]=a.y; v[2]=a.z; v[3]=a.w; v[4]=b.x; v[5]=b.y; v[6]=b.z; v[7]=b.w;
    } else {
        for (int i = 0; i < 8; ++i) v[i] = 0.f;
    }
    unsigned short o[8];
    for (int i = 0; i < 8; ++i) o[i] = f2bf(v[i]);
    *reinterpret_cast<short8*>(&F[(size_t)row * KPAD1 + col]) =
        *reinterpret_cast<const short8*>(o);
}

__global__ __launch_bounds__(256) void convert_wT_kernel(
    const float* __restrict__ W, unsigned short* __restrict__ WT,
    int K, int N, int Kpad)
{
    const int t = blockIdx.x * 256 + threadIdx.x;
    if (t >= N * Kpad) return;
    const int n = t / Kpad;
    const int k = t - n * Kpad;
    WT[t] = (k < K) ? f2bf(W[(size_t)k * N + n]) : (unsigned short)0;
}

// ================= bf16 MFMA GEMM (unchanged from r5) ======================
template <int EPI>
__global__ __launch_bounds__(256) void gemm_bf16_kernel(
    const unsigned short* __restrict__ A, const unsigned short* __restrict__ BT,
    const float* __restrict__ bias, void* __restrict__ outv, int N, int K)
{
    __shared__ unsigned short As[128 * 64];
    __shared__ unsigned short Bs[64 * 64];

    const int tid = threadIdx.x;
    const int lane = tid & 63;
    const int wid = tid >> 6;
    const int wm = wid >> 1;
    const int wn = wid & 1;
    const int m0 = blockIdx.y * 128;
    const int n0 = blockIdx.x * 64;

    const int srow = lane >> 3;
    const int schunk = lane & 7;
    const int sswz = schunk ^ srow;

    f32x4 acc[4][2];
#pragma unroll
    for (int i = 0; i < 4; ++i)
#pragma unroll
        for (int j = 0; j < 2; ++j) acc[i][j] = (f32x4)0.f;

    for (int k0 = 0; k0 < K; k0 += 64) {
#pragma unroll
        for (int i = 0; i < 4; ++i) {
            const int r = wid * 32 + i * 8 + srow;
            const short8 v = *reinterpret_cast<const short8*>(
                &A[(size_t)(m0 + r) * K + k0 + sswz * 8]);
            *reinterpret_cast<short8*>(&As[r * 64 + schunk * 8]) = v;
        }
#pragma unroll
        for (int i = 0; i < 2; ++i) {
            const int r = wid * 16 + i * 8 + srow;
            const short8 v = *reinterpret_cast<const short8*>(
                &BT[(size_t)(n0 + r) * K + k0 + sswz * 8]);
            *reinterpret_cast<short8*>(&Bs[r * 64 + schunk * 8]) = v;
        }
        __syncthreads();

#pragma unroll
        for (int ks = 0; ks < 2; ++ks) {
            short8 af[4], bf[2];
            const int c = ks * 4 + (lane >> 4);
#pragma unroll
            for (int fm = 0; fm < 4; ++fm) {
                const int r = wm * 64 + fm * 16 + (lane & 15);
                af[fm] = *reinterpret_cast<const short8*>(
                    &As[r * 64 + (c ^ (r & 7)) * 8]);
            }
#pragma unroll
            for (int fn = 0; fn < 2; ++fn) {
                const int r = wn * 32 + fn * 16 + (lane & 15);
                bf[fn] = *reinterpret_cast<const short8*>(
                    &Bs[r * 64 + (c ^ (r & 7)) * 8]);
            }
#pragma unroll
            for (int fm = 0; fm < 4; ++fm)
#pragma unroll
                for (int fn = 0; fn < 2; ++fn)
                    acc[fm][fn] = __builtin_amdgcn_mfma_f32_16x16x32_bf16(
                        af[fm], bf[fn], acc[fm][fn], 0, 0, 0);
        }
        __syncthreads();
    }

    // C/D layout: col = lane&15, row = (lane>>4)*4 + reg
#pragma unroll
    for (int fn = 0; fn < 2; ++fn) {
        const int col = n0 + wn * 32 + fn * 16 + (lane & 15);
        const float bv = bias[col];
#pragma unroll
        for (int fm = 0; fm < 4; ++fm) {
            const int rbase = m0 + wm * 64 + fm * 16 + (lane >> 4) * 4;
#pragma unroll
            for (int e = 0; e < 4; ++e) {
                const float v = acc[fm][fn][e] + bv;
                if (EPI == 0) {
                    unsigned short* h = (unsigned short*)outv;
                    h[(size_t)(rbase + e) * N + col] = f2bf(fmaxf(v, 0.f));
                } else {
                    float* out = (float*)outv;
                    const int p = col >> 10;
                    const int w = col & 1023;
                    out[(size_t)p * EDGES + (size_t)(rbase + e) * OUT_DIM + w] =
                        __expf(v);
                }
            }
        }
    }
}

// ============ scatter WITH VALUES: coalesced e-read, binned record write ===
// idx0 record (u64): seg9 << 32 | e0_bf16 << 16 | e1_bf16
__global__ __launch_bounds__(256) void scatter01_kernel(
    const int* __restrict__ idx, const float* __restrict__ out, int w0,
    unsigned long long* __restrict__ P, unsigned* __restrict__ cursor)
{
    __shared__ unsigned hist[BINS];
    __shared__ unsigned offs[BINS];
    const int tid = threadIdx.x;
    const int base = w0 + blockIdx.x * SCHUNK;

    for (int b = tid; b < BINS; b += 256) { hist[b] = 0; offs[b] = 0; }
    __syncthreads();

#pragma unroll 4
    for (int i = 0; i < SCHUNK / 256; ++i) {
        const int seg = idx[base + i * 256 + tid];
        atomicAdd(&hist[seg >> 9], 1u);
    }
    __syncthreads();

    for (int b = tid; b < BINS; b += 256)
        hist[b] = atomicAdd(&cursor[b], hist[b]);   // reserve; hist := base
    __syncthreads();

#pragma unroll 4
    for (int i = 0; i < SCHUNK / 256; ++i) {
        const int w = base + i * 256 + tid;
        const int seg = idx[w];
        const int b = seg >> 9;
        const float e0 = out[w];                    // coalesced
        const float e1 = out[(size_t)EDGES + w];    // coalesced
        const unsigned o = atomicAdd(&offs[b], 1u);
        const unsigned pos = hist[b] + o;
        if (pos < BIN_CAP01) {                      // overflow guard (P~1e-50)
            const unsigned lo = ((unsigned)f2bf(e0) << 16) | f2bf(e1);
            P[(size_t)b * BIN_CAP01 + pos] =
                ((unsigned long long)(seg & 511) << 32) | lo;
        }
    }
}

// idx1 record (u32): seg9 << 16 | e2_bf16
__global__ __launch_bounds__(256) void scatter2_kernel(
    const int* __restrict__ idx, const float* __restrict__ out, int w0,
    unsigned* __restrict__ P, unsigned* __restrict__ cursor)
{
    __shared__ unsigned hist[BINS];
    __shared__ unsigned offs[BINS];
    const int tid = threadIdx.x;
    const int base = w0 + blockIdx.x * SCHUNK;

    for (int b = tid; b < BINS; b += 256) { hist[b] = 0; offs[b] = 0; }
    __syncthreads();

#pragma unroll 4
    for (int i = 0; i < SCHUNK / 256; ++i) {
        const int seg = idx[base + i * 256 + tid];
        atomicAdd(&hist[seg >> 9], 1u);
    }
    __syncthreads();

    for (int b = tid; b < BINS; b += 256)
        hist[b] = atomicAdd(&cursor[b], hist[b]);
    __syncthreads();

#pragma unroll 4
    for (int i = 0; i < SCHUNK / 256; ++i) {
        const int w = base + i * 256 + tid;
        const int seg = idx[w];
        const int b = seg >> 9;
        const float e2 = out[2 * (size_t)EDGES + w];   // coalesced
        const unsigned o = atomicAdd(&offs[b], 1u);
        const unsigned pos = hist[b] + o;
        if (pos < BIN_CAP2)
            P[(size_t)b * BIN_CAP2 + pos] =
                ((unsigned)(seg & 511) << 16) | f2bf(e2);
    }
}

// ============ per-bin reduce: pure coalesced + LDS, no random access =======
__global__ __launch_bounds__(256) void reduce01v_kernel(
    const unsigned long long* __restrict__ P,
    const unsigned* __restrict__ cursor, float2* __restrict__ s01, int accum)
{
    __shared__ float sub0[SEGS_PER_BIN];
    __shared__ float sub1[SEGS_PER_BIN];
    const int b = blockIdx.x;
    const int tid = threadIdx.x;
    for (int i = tid; i < SEGS_PER_BIN; i += 256) { sub0[i] = 0.f; sub1[i] = 0.f; }
    __syncthreads();

    const int cnt = min((int)cursor[b], BIN_CAP01);
    const unsigned long long* rec = &P[(size_t)b * BIN_CAP01];
    for (int i = tid; i < cnt; i += 256) {
        const unsigned long long r = rec[i];
        const int sl = (int)(r >> 32);
        const unsigned lo = (unsigned)r;
        atomicAdd(&sub0[sl], __uint_as_float(lo & 0xffff0000u));
        atomicAdd(&sub1[sl], __uint_as_float(lo << 16));
    }
    __syncthreads();

    for (int i = tid; i < SEGS_PER_BIN; i += 256) {
        const int seg = b * SEGS_PER_BIN + i;
        float2 v = make_float2(sub0[i], sub1[i]);
        if (accum) { const float2 p = s01[seg]; v.x += p.x; v.y += p.y; }
        s01[seg] = v;
    }
}

__global__ __launch_bounds__(256) void reduce2v_kernel(
    const unsigned* __restrict__ P, const unsigned* __restrict__ cursor,
    float* __restrict__ s2, int accum)
{
    __shared__ float sub[SEGS_PER_BIN];
    const int b = blockIdx.x;
    const int tid = threadIdx.x;
    for (int i = tid; i < SEGS_PER_BIN; i += 256) sub[i] = 0.f;
    __syncthreads();

    const int cnt = min((int)cursor[b], BIN_CAP2);
    const unsigned* rec = &P[(size_t)b * BIN_CAP2];
    for (int i = tid; i < cnt; i += 256) {
        const unsigned r = rec[i];
        atomicAdd(&sub[r >> 16], __uint_as_float(r << 16));
    }
    __syncthreads();

    for (int i = tid; i < SEGS_PER_BIN; i += 256) {
        const int seg = b * SEGS_PER_BIN + i;
        float v = sub[i];
        if (accum) v += s2[seg];
        s2[seg] = v;
    }
}

// ================= softmax finish ==========================================
__global__ __launch_bounds__(256) void recip_kernel(float2* __restrict__ s01,
                                                    float* __restrict__ s2) {
    const int i = blockIdx.x * blockDim.x + threadIdx.x;
    if (i >= NSEG) return;
    const float2 v = s01[i];
    s01[i] = make_float2(1.f / v.x, 1.f / v.y);
    s2[i] = 1.f / s2[i];
}

__global__ __launch_bounds__(256) void segdiv_kernel(
    float* __restrict__ vals, const int* __restrict__ idx0,
    const int* __restrict__ idx1, const float2* __restrict__ r01,
    const float* __restrict__ r2) {
    const int w = blockIdx.x * blockDim.x + threadIdx.x;
    if (w >= EDGES) return;
    const float2 rv = r01[idx0[w]];
    const float rc = r2[idx1[w]];
    vals[w] *= rv.x;
    vals[EDGES + w] *= rv.y;
    vals[2 * (size_t)EDGES + w] *= rc;
}

// ===========================================================================
extern "C" void kernel_launch(void* const* d_in, const int* in_sizes, int n_in,
                              void* d_out, int out_size, void* d_ws,
                              size_t ws_size, hipStream_t stream) {
    const float* u2s = (const float*)d_in[0];
    const float* usr = (const float*)d_in[1];
    const float* srv = (const float*)d_in[2];
    const int* edge = (const int*)d_in[3];
    const float* W1 = (const float*)d_in[4];
    const float* b1 = (const float*)d_in[5];
    const float* W2 = (const float*)d_in[6];
    const float* b2 = (const float*)d_in[7];
    const float* W3 = (const float*)d_in[8];
    const float* b3 = (const float*)d_in[9];
    const float* W4 = (const float*)d_in[10];
    const float* b4 = (const float*)d_in[11];

    const int* idx0 = edge;
    const int* idx1 = edge + EDGES;

    // ws layout (38 MiB max, 38.4 proven):
    //  phase1: F [0,19.9) | h1 [20,24) | h2 [24,28) | h3 [28,32) | wT [32,34.4)
    //  phase2: P [0,24) | cursor [24,24.008) | s01 [26,34) | s2 [34,38)
    //  (phase2 regions only written after their phase1 occupants are dead)
    char* ws = (char*)d_ws;
    unsigned short* F = (unsigned short*)ws;
    unsigned short* h1 = (unsigned short*)(ws + 20u * 1024 * 1024);
    unsigned short* h2 = (unsigned short*)(ws + 24u * 1024 * 1024);
    unsigned short* h3 = (unsigned short*)(ws + 28u * 1024 * 1024);
    unsigned short* w1t = (unsigned short*)(ws + 32u * 1024 * 1024);
    unsigned short* w2t = w1t + (size_t)HID * KPAD1;
    unsigned short* w3t = w2t + (size_t)HID * HID;
    unsigned short* w4t = w3t + (size_t)HID * HID;

    unsigned long long* P64 = (unsigned long long*)ws;
    unsigned* P32 = (unsigned*)ws;
    unsigned* cursor = (unsigned*)(ws + 24u * 1024 * 1024);
    float2* s01 = (float2*)(ws + 26u * 1024 * 1024);
    float* s2 = (float*)(ws + 34u * 1024 * 1024);
    float* outp = (float*)d_out;

    const dim3 blk(256);

    // ---- prep: conversions ----
    convert_feats_kernel<<<(B_GRAPHS * 152) / 256, blk, 0, stream>>>(u2s, usr,
                                                                     srv, F);
    convert_wT_kernel<<<(HID * KPAD1 + 255) / 256, blk, 0, stream>>>(
        W1, w1t, IN_DIM, HID, KPAD1);
    convert_wT_kernel<<<(HID * HID + 255) / 256, blk, 0, stream>>>(
        W2, w2t, HID, HID, HID);
    convert_wT_kernel<<<(HID * HID + 255) / 256, blk, 0, stream>>>(
        W3, w3t, HID, HID, HID);
    convert_wT_kernel<<<(3 * OUT_DIM * HID + 255) / 256, blk, 0, stream>>>(
        W4, w4t, HID, 3 * OUT_DIM, HID);

    // ---- MLP (bf16 MFMA) ----
    gemm_bf16_kernel<0><<<dim3(HID / 64, B_GRAPHS / 128), blk, 0, stream>>>(
        F, w1t, b1, h1, HID, KPAD1);
    gemm_bf16_kernel<0><<<dim3(HID / 64, B_GRAPHS / 128), blk, 0, stream>>>(
        h1, w2t, b2, h2, HID, HID);
    gemm_bf16_kernel<0><<<dim3(HID / 64, B_GRAPHS / 128), blk, 0, stream>>>(
        h2, w3t, b3, h3, HID, HID);
    gemm_bf16_kernel<1><<<dim3(3 * OUT_DIM / 64, B_GRAPHS / 128), blk, 0,
                          stream>>>(h3, w4t, b4, outp, 3 * OUT_DIM, HID);

    // ---- segment sums: value-carrying scatter + coalesced bin reduce ----
    for (int q = 0; q < 4; ++q) {
        hipMemsetAsync(cursor, 0, BINS * sizeof(unsigned), stream);
        scatter01_kernel<<<QUARTER / SCHUNK, blk, 0, stream>>>(
            idx0, outp, q * QUARTER, P64, cursor);
        reduce01v_kernel<<<BINS, blk, 0, stream>>>(P64, cursor, s01, q);
    }
    for (int h = 0; h < 2; ++h) {
        hipMemsetAsync(cursor, 0, BINS * sizeof(unsigned), stream);
        scatter2_kernel<<<HALF / SCHUNK, blk, 0, stream>>>(
            idx1, outp, h * HALF, P32, cursor);
        reduce2v_kernel<<<BINS, blk, 0, stream>>>(P32, cursor, s2, h);
    }

    recip_kernel<<<(NSEG + 255) / 256, blk, 0, stream>>>(s01, s2);
    segdiv_kernel<<<(EDGES + 255) / 256, blk, 0, stream>>>(outp, idx0, idx1,
                                                           s01, s2);
}

// Round 7
// 730.952 us; speedup vs baseline: 1.2141x; 1.2141x over previous
//
#include <hip/hip_runtime.h>
#include <math.h>

#define B_GRAPHS 8192
#define OUT_DIM 1024
#define NU 128
#define NS 8
#define IN_DIM 1160          // OUT_DIM + NU + NS
#define KPAD1 1216           // IN_DIM padded to multiple of 64
#define HID 256
#define NSEG (B_GRAPHS * NU)        // 1048576 = 2^20
#define EDGES (B_GRAPHS * OUT_DIM)  // 8388608 = 2^23

// ---- binning parameters ----
#define BINS 2048
#define SEGS_PER_BIN 512
#define HALF (EDGES / 2)            // 4194304 edges per pass
#define BIN_CAP 2432                // mean 2048 + 8.5 sigma; 2048*2432*4B = 19.0MiB (= F size)
#define SCHUNK 16384                // edges per scatter block

typedef __attribute__((ext_vector_type(8))) short short8;
typedef __attribute__((ext_vector_type(4))) float f32x4;

__device__ __forceinline__ unsigned short f2bf(float f) {
    unsigned u = __float_as_uint(f);
    const unsigned r = (u >> 16) & 1u;
    return (unsigned short)((u + 0x7fffu + r) >> 16);   // RNE
}
__device__ __forceinline__ float bf2f(unsigned short b) {
    return __uint_as_float((unsigned)b << 16);
}

// ================= prep: fp32 -> bf16 conversions ==========================
__global__ __launch_bounds__(256) void convert_feats_kernel(
    const float* __restrict__ u2s, const float* __restrict__ usr,
    const float* __restrict__ srv, unsigned short* __restrict__ F)
{
    const int t = blockIdx.x * 256 + threadIdx.x;   // 8192*152 threads
    const int row = t / 152;
    const int g = t - row * 152;
    const int col = g * 8;
    float v[8];
    if (g < 128) {
        const float4 a = *(const float4*)&u2s[(size_t)row * OUT_DIM + col];
        const float4 b = *(const float4*)&u2s[(size_t)row * OUT_DIM + col + 4];
        v[0]=a.x; v[1]=a.y; v[2]=a.z; v[3]=a.w; v[4]=b.x; v[5]=b.y; v[6]=b.z; v[7]=b.w;
    } else if (g < 144) {
        const int c = col - OUT_DIM;
        const float4 a = *(const float4*)&usr[(size_t)row * NU + c];
        const float4 b = *(const float4*)&usr[(size_t)row * NU + c + 4];
        v[0]=a.x; v[1]=a.y; v[2]=a.z; v[3]=a.w; v[4]=b.x; v[5]=b.y; v[6]=b.z; v[7]=b.w;
    } else if (g == 144) {
        const float4 a = *(const float4*)&srv[(size_t)row * NS];
        const float4 b = *(const float4*)&srv[(size_t)row * NS + 4];
        v[0]=a.x; v[1]=a.y; v[2]=a.z; v[3]=a.w; v[4]=b.x; v[5]=b.y; v[6]=b.z; v[7]=b.w;
    } else {
        for (int i = 0; i < 8; ++i) v[i] = 0.f;
    }
    unsigned short o[8];
    for (int i = 0; i < 8; ++i) o[i] = f2bf(v[i]);
    *reinterpret_cast<short8*>(&F[(size_t)row * KPAD1 + col]) =
        *reinterpret_cast<const short8*>(o);
}

__global__ __launch_bounds__(256) void convert_wT_kernel(
    const float* __restrict__ W, unsigned short* __restrict__ WT,
    int K, int N, int Kpad)
{
    const int t = blockIdx.x * 256 + threadIdx.x;
    if (t >= N * Kpad) return;
    const int n = t / Kpad;
    const int k = t - n * Kpad;
    WT[t] = (k < K) ? f2bf(W[(size_t)k * N + n]) : (unsigned short)0;
}

// ================= bf16 MFMA GEMM (r5-proven) ==============================
template <int EPI>
__global__ __launch_bounds__(256) void gemm_bf16_kernel(
    const unsigned short* __restrict__ A, const unsigned short* __restrict__ BT,
    const float* __restrict__ bias, void* __restrict__ outv, int N, int K)
{
    __shared__ unsigned short As[128 * 64];
    __shared__ unsigned short Bs[64 * 64];

    const int tid = threadIdx.x;
    const int lane = tid & 63;
    const int wid = tid >> 6;
    const int wm = wid >> 1;
    const int wn = wid & 1;
    const int m0 = blockIdx.y * 128;
    const int n0 = blockIdx.x * 64;

    const int srow = lane >> 3;
    const int schunk = lane & 7;
    const int sswz = schunk ^ srow;

    f32x4 acc[4][2];
#pragma unroll
    for (int i = 0; i < 4; ++i)
#pragma unroll
        for (int j = 0; j < 2; ++j) acc[i][j] = (f32x4)0.f;

    for (int k0 = 0; k0 < K; k0 += 64) {
#pragma unroll
        for (int i = 0; i < 4; ++i) {
            const int r = wid * 32 + i * 8 + srow;
            const short8 v = *reinterpret_cast<const short8*>(
                &A[(size_t)(m0 + r) * K + k0 + sswz * 8]);
            *reinterpret_cast<short8*>(&As[r * 64 + schunk * 8]) = v;
        }
#pragma unroll
        for (int i = 0; i < 2; ++i) {
            const int r = wid * 16 + i * 8 + srow;
            const short8 v = *reinterpret_cast<const short8*>(
                &BT[(size_t)(n0 + r) * K + k0 + sswz * 8]);
            *reinterpret_cast<short8*>(&Bs[r * 64 + schunk * 8]) = v;
        }
        __syncthreads();

#pragma unroll
        for (int ks = 0; ks < 2; ++ks) {
            short8 af[4], bf[2];
            const int c = ks * 4 + (lane >> 4);
#pragma unroll
            for (int fm = 0; fm < 4; ++fm) {
                const int r = wm * 64 + fm * 16 + (lane & 15);
                af[fm] = *reinterpret_cast<const short8*>(
                    &As[r * 64 + (c ^ (r & 7)) * 8]);
            }
#pragma unroll
            for (int fn = 0; fn < 2; ++fn) {
                const int r = wn * 32 + fn * 16 + (lane & 15);
                bf[fn] = *reinterpret_cast<const short8*>(
                    &Bs[r * 64 + (c ^ (r & 7)) * 8]);
            }
#pragma unroll
            for (int fm = 0; fm < 4; ++fm)
#pragma unroll
                for (int fn = 0; fn < 2; ++fn)
                    acc[fm][fn] = __builtin_amdgcn_mfma_f32_16x16x32_bf16(
                        af[fm], bf[fn], acc[fm][fn], 0, 0, 0);
        }
        __syncthreads();
    }

    // C/D layout: col = lane&15, row = (lane>>4)*4 + reg
#pragma unroll
    for (int fn = 0; fn < 2; ++fn) {
        const int col = n0 + wn * 32 + fn * 16 + (lane & 15);
        const float bv = bias[col];
#pragma unroll
        for (int fm = 0; fm < 4; ++fm) {
            const int rbase = m0 + wm * 64 + fm * 16 + (lane >> 4) * 4;
#pragma unroll
            for (int e = 0; e < 4; ++e) {
                const float v = acc[fm][fn][e] + bv;
                if (EPI == 0) {
                    unsigned short* h = (unsigned short*)outv;
                    h[(size_t)(rbase + e) * N + col] = f2bf(fmaxf(v, 0.f));
                } else {
                    float* out = (float*)outv;
                    const int p = col >> 10;
                    const int w = col & 1023;
                    out[(size_t)p * EDGES + (size_t)(rbase + e) * OUT_DIM + w] =
                        __expf(v);
                }
            }
        }
    }
}

// ============ scatter: (seg,w) u32 records into seg-high-bit bins ==========
// record u32 = (seg & 511) << 23 | w
__global__ __launch_bounds__(256) void scatter_kernel(
    const int* __restrict__ idx, int w0, unsigned* __restrict__ P,
    unsigned* __restrict__ cursor)
{
    __shared__ unsigned hist[BINS];
    __shared__ unsigned offs[BINS];
    const int tid = threadIdx.x;
    const int base = w0 + blockIdx.x * SCHUNK;

    for (int b = tid; b < BINS; b += 256) { hist[b] = 0; offs[b] = 0; }
    __syncthreads();

#pragma unroll 4
    for (int i = 0; i < SCHUNK / 256; ++i) {
        const int seg = idx[base + i * 256 + tid];
        atomicAdd(&hist[seg >> 9], 1u);
    }
    __syncthreads();

    for (int b = tid; b < BINS; b += 256)
        hist[b] = atomicAdd(&cursor[b], hist[b]);   // reserve; hist := base
    __syncthreads();

#pragma unroll 4
    for (int i = 0; i < SCHUNK / 256; ++i) {
        const int w = base + i * 256 + tid;          // second read: L2 hit
        const int seg = idx[w];
        const int b = seg >> 9;
        const unsigned o = atomicAdd(&offs[b], 1u);
        const unsigned pos = hist[b] + o;
        if (pos < BIN_CAP)                           // overflow guard
            P[(size_t)b * BIN_CAP + pos] =
                ((unsigned)(seg & 511) << 23) | (unsigned)w;
    }
}

// ============ per-bin reduce; last pass writes reciprocal tables ===========
__global__ __launch_bounds__(256) void reduce01_kernel(
    const unsigned* __restrict__ P, const unsigned* __restrict__ cursor,
    const float* __restrict__ out, float2* __restrict__ s01,
    unsigned* __restrict__ r01, int last, int fast)
{
    __shared__ float sub0[SEGS_PER_BIN];
    __shared__ float sub1[SEGS_PER_BIN];
    const int b = blockIdx.x;
    const int tid = threadIdx.x;
    for (int i = tid; i < SEGS_PER_BIN; i += 256) { sub0[i] = 0.f; sub1[i] = 0.f; }
    __syncthreads();

    const int cnt = min((int)cursor[b], BIN_CAP);
    const unsigned* rec = &P[(size_t)b * BIN_CAP];
    for (int i = tid; i < cnt; i += 256) {
        const unsigned r = rec[i];
        const int w = r & 0x7FFFFF;
        const int sl = r >> 23;
        atomicAdd(&sub0[sl], out[w]);
        atomicAdd(&sub1[sl], out[(size_t)EDGES + w]);
    }
    __syncthreads();

    for (int i = tid; i < SEGS_PER_BIN; i += 256) {
        const int seg = b * SEGS_PER_BIN + i;
        float2 v = make_float2(sub0[i], sub1[i]);
        if (!last) {
            s01[seg] = v;                       // pass 0: raw sums
        } else {
            const float2 p = s01[seg];
            const float rx = 1.f / (v.x + p.x);
            const float ry = 1.f / (v.y + p.y);
            if (fast)
                r01[seg] = ((unsigned)f2bf(rx) << 16) | f2bf(ry);
            else
                s01[seg] = make_float2(rx, ry); // in-place recip (fallback)
        }
    }
}

__global__ __launch_bounds__(256) void reduce2_kernel(
    const unsigned* __restrict__ P, const unsigned* __restrict__ cursor,
    const float* __restrict__ out, float* __restrict__ s2,
    unsigned short* __restrict__ r2, int last, int fast)
{
    __shared__ float sub[SEGS_PER_BIN];
    const int b = blockIdx.x;
    const int tid = threadIdx.x;
    for (int i = tid; i < SEGS_PER_BIN; i += 256) sub[i] = 0.f;
    __syncthreads();

    const int cnt = min((int)cursor[b], BIN_CAP);
    const unsigned* rec = &P[(size_t)b * BIN_CAP];
    for (int i = tid; i < cnt; i += 256) {
        const unsigned r = rec[i];
        const int w = r & 0x7FFFFF;
        atomicAdd(&sub[r >> 23], out[2 * (size_t)EDGES + w]);
    }
    __syncthreads();

    for (int i = tid; i < SEGS_PER_BIN; i += 256) {
        const int seg = b * SEGS_PER_BIN + i;
        const float v = sub[i];
        if (!last) {
            s2[seg] = v;
        } else {
            const float rc = 1.f / (v + s2[seg]);
            if (fast) r2[seg] = f2bf(rc);
            else      s2[seg] = rc;
        }
    }
}

// ============ normalize, split per table for L2 residency ==================
// sections 0,1: random set = r01 (4MB bf16-pair fast path)
__global__ __launch_bounds__(256) void segdiv01_kernel(
    float* __restrict__ vals, const int* __restrict__ idx0,
    const unsigned* __restrict__ r01, const float2* __restrict__ s01, int fast)
{
    const int w4 = (blockIdx.x * 256 + threadIdx.x) * 4;
    if (w4 >= EDGES) return;
    const int4 iv = *reinterpret_cast<const int4*>(&idx0[w4]);
    const int idx[4] = {iv.x, iv.y, iv.z, iv.w};
    float4 a = *reinterpret_cast<const float4*>(&vals[w4]);
    float4 b = *reinterpret_cast<const float4*>(&vals[(size_t)EDGES + w4]);
    float r0[4], r1[4];
#pragma unroll
    for (int j = 0; j < 4; ++j) {
        if (fast) {
            const unsigned p = r01[idx[j]];
            r0[j] = __uint_as_float(p & 0xffff0000u);
            r1[j] = __uint_as_float(p << 16);
        } else {
            const float2 rv = s01[idx[j]];
            r0[j] = rv.x; r1[j] = rv.y;
        }
    }
    a.x *= r0[0]; a.y *= r0[1]; a.z *= r0[2]; a.w *= r0[3];
    b.x *= r1[0]; b.y *= r1[1]; b.z *= r1[2]; b.w *= r1[3];
    *reinterpret_cast<float4*>(&vals[w4]) = a;
    *reinterpret_cast<float4*>(&vals[(size_t)EDGES + w4]) = b;
}

// section 2: random set = r2 (2MB bf16 fast path)
__global__ __launch_bounds__(256) void segdiv2_kernel(
    float* __restrict__ vals, const int* __restrict__ idx1,
    const unsigned short* __restrict__ r2, const float* __restrict__ s2,
    int fast)
{
    const int w4 = (blockIdx.x * 256 + threadIdx.x) * 4;
    if (w4 >= EDGES) return;
    const int4 iv = *reinterpret_cast<const int4*>(&idx1[w4]);
    const int idx[4] = {iv.x, iv.y, iv.z, iv.w};
    float4 c = *reinterpret_cast<const float4*>(&vals[2 * (size_t)EDGES + w4]);
    float rc[4];
#pragma unroll
    for (int j = 0; j < 4; ++j)
        rc[j] = fast ? bf2f(r2[idx[j]]) : s2[idx[j]];
    c.x *= rc[0]; c.y *= rc[1]; c.z *= rc[2]; c.w *= rc[3];
    *reinterpret_cast<float4*>(&vals[2 * (size_t)EDGES + w4]) = c;
}

// ===========================================================================
extern "C" void kernel_launch(void* const* d_in, const int* in_sizes, int n_in,
                              void* d_out, int out_size, void* d_ws,
                              size_t ws_size, hipStream_t stream) {
    const float* u2s = (const float*)d_in[0];
    const float* usr = (const float*)d_in[1];
    const float* srv = (const float*)d_in[2];
    const int* edge = (const int*)d_in[3];
    const float* W1 = (const float*)d_in[4];
    const float* b1 = (const float*)d_in[5];
    const float* W2 = (const float*)d_in[6];
    const float* b2 = (const float*)d_in[7];
    const float* W3 = (const float*)d_in[8];
    const float* b3 = (const float*)d_in[9];
    const float* W4 = (const float*)d_in[10];
    const float* b4 = (const float*)d_in[11];

    const int* idx0 = edge;
    const int* idx1 = edge + EDGES;

    // ws layout:
    //  phase1: F [0,19.0MiB) | h1 [20,24) | h2 [24,28) | h3 [28,32) | wT [32,34.4)
    //  phase2: P [0,19.0) | cursor @20MiB | s01 [24,32) | s2 [32,36)
    //  fast tables (if ws_size >= 43MiB): r01 (4MiB) + r2 (2MiB) at end of ws
    char* ws = (char*)d_ws;
    unsigned short* F = (unsigned short*)ws;
    unsigned short* h1 = (unsigned short*)(ws + 20ull * 1024 * 1024);
    unsigned short* h2 = (unsigned short*)(ws + 24ull * 1024 * 1024);
    unsigned short* h3 = (unsigned short*)(ws + 28ull * 1024 * 1024);
    unsigned short* w1t = (unsigned short*)(ws + 32ull * 1024 * 1024);
    unsigned short* w2t = w1t + (size_t)HID * KPAD1;
    unsigned short* w3t = w2t + (size_t)HID * HID;
    unsigned short* w4t = w3t + (size_t)HID * HID;

    unsigned* P = (unsigned*)ws;
    unsigned* cursor = (unsigned*)(ws + 20ull * 1024 * 1024);
    float2* s01 = (float2*)(ws + 24ull * 1024 * 1024);
    float* s2 = (float*)(ws + 32ull * 1024 * 1024);

    const int fast = (ws_size >= 43ull * 1024 * 1024) ? 1 : 0;
    const size_t tab_base = (ws_size - 6ull * 1024 * 1024) & ~(size_t)255;
    unsigned* r01 = (unsigned*)(ws + (fast ? tab_base : 0));
    unsigned short* r2 =
        (unsigned short*)(ws + (fast ? tab_base + 4ull * 1024 * 1024 : 0));

    float* outp = (float*)d_out;
    const dim3 blk(256);

    // ---- prep: conversions ----
    convert_feats_kernel<<<(B_GRAPHS * 152) / 256, blk, 0, stream>>>(u2s, usr,
                                                                     srv, F);
    convert_wT_kernel<<<(HID * KPAD1 + 255) / 256, blk, 0, stream>>>(
        W1, w1t, IN_DIM, HID, KPAD1);
    convert_wT_kernel<<<(HID * HID + 255) / 256, blk, 0, stream>>>(
        W2, w2t, HID, HID, HID);
    convert_wT_kernel<<<(HID * HID + 255) / 256, blk, 0, stream>>>(
        W3, w3t, HID, HID, HID);
    convert_wT_kernel<<<(3 * OUT_DIM * HID + 255) / 256, blk, 0, stream>>>(
        W4, w4t, HID, 3 * OUT_DIM, HID);

    // ---- MLP (bf16 MFMA) ----
    gemm_bf16_kernel<0><<<dim3(HID / 64, B_GRAPHS / 128), blk, 0, stream>>>(
        F, w1t, b1, h1, HID, KPAD1);
    gemm_bf16_kernel<0><<<dim3(HID / 64, B_GRAPHS / 128), blk, 0, stream>>>(
        h1, w2t, b2, h2, HID, HID);
    gemm_bf16_kernel<0><<<dim3(HID / 64, B_GRAPHS / 128), blk, 0, stream>>>(
        h2, w3t, b3, h3, HID, HID);
    gemm_bf16_kernel<1><<<dim3(3 * OUT_DIM / 64, B_GRAPHS / 128), blk, 0,
                          stream>>>(h3, w4t, b4, outp, 3 * OUT_DIM, HID);

    // ---- segment sums: bin-scatter-reduce; last pass emits recip tables ---
    for (int h = 0; h < 2; ++h) {
        hipMemsetAsync(cursor, 0, BINS * sizeof(unsigned), stream);
        scatter_kernel<<<HALF / SCHUNK, blk, 0, stream>>>(idx0, h * HALF, P,
                                                          cursor);
        reduce01_kernel<<<BINS, blk, 0, stream>>>(P, cursor, outp, s01, r01,
                                                  h, fast);
    }
    for (int h = 0; h < 2; ++h) {
        hipMemsetAsync(cursor, 0, BINS * sizeof(unsigned), stream);
        scatter_kernel<<<HALF / SCHUNK, blk, 0, stream>>>(idx1, h * HALF, P,
                                                          cursor);
        reduce2_kernel<<<BINS, blk, 0, stream>>>(P, cursor, outp, s2, r2, h,
                                                 fast);
    }

    // ---- normalize (split so each pass's random table fits one L2) ----
    segdiv01_kernel<<<EDGES / 1024, blk, 0, stream>>>(outp, idx0, r01, s01,
                                                      fast);
    segdiv2_kernel<<<EDGES / 1024, blk, 0, stream>>>(outp, idx1, r2, s2, fast);
}